// Round 2
// baseline (165.880 us; speedup 1.0000x reference)
//
#include <hip/hip_runtime.h>
#include <math.h>

#define NBLK 2048
#define NTHR 256

// q fields: .x=w .y=x .z=y .w=z  (reference layout q[:,0..3] = w,x,y,z)
// Unnormalized rotation of REF=(0,0,1) by q:  u = |q|^2 * R(q_hat)*REF
//   u = ( 2(w*y + x*z), 2(y*z - w*x), |q|^2 - 2(x^2 + y^2) )
// The |q|^2 factor cancels under the final normalization.
__device__ __forceinline__ float row_angle2(float4 p, float4 t) {
    float n2p = p.x*p.x + p.y*p.y + p.z*p.z + p.w*p.w;
    float upx = 2.0f*(p.x*p.z + p.y*p.w);
    float upy = 2.0f*(p.z*p.w - p.x*p.y);
    float upz = n2p - 2.0f*(p.y*p.y + p.z*p.z);

    float n2t = t.x*t.x + t.y*t.y + t.z*t.z + t.w*t.w;
    float utx = 2.0f*(t.x*t.z + t.y*t.w);
    float uty = 2.0f*(t.z*t.w - t.x*t.y);
    float utz = n2t - 2.0f*(t.y*t.y + t.z*t.z);

    float d   = upx*utx + upy*uty + upz*utz;
    float mp  = upx*upx + upy*upy + upz*upz;
    float mt  = utx*utx + uty*uty + utz*utz;
    float m   = fmaxf(mp*mt, 1e-24f);
    float c   = d * rsqrtf(m);
    c = fminf(1.0f, fmaxf(-1.0f, c));

    // acos via Abramowitz-Stegun 4.4.45: |err| <= 6.7e-5 rad
    float a = fabsf(c);
    float r = sqrtf(1.0f - a) *
              (1.5707288f + a*(-0.2121144f + a*(0.0742610f + a*(-0.0187293f))));
    float ang = (c >= 0.0f) ? r : 3.14159265358979f - r;
    return ang * ang;
}

__global__ __launch_bounds__(NTHR) void drl_fused(
    const float4* __restrict__ pred,
    const float4* __restrict__ targ,
    float* __restrict__ partial,
    int*  __restrict__ counter,
    float* __restrict__ out,
    int B, float invB)
{
    const int stride = gridDim.x * blockDim.x;
    float acc = 0.0f;
    int i = blockIdx.x * blockDim.x + threadIdx.x;
    for (; i + stride < B; i += 2*stride) {
        float4 p0 = pred[i],        t0 = targ[i];
        float4 p1 = pred[i+stride], t1 = targ[i+stride];
        acc += row_angle2(p0, t0);
        acc += row_angle2(p1, t1);
    }
    if (i < B) acc += row_angle2(pred[i], targ[i]);

    // intra-block reduce: wave64 shfl tree -> LDS across 4 waves
    #pragma unroll
    for (int off = 32; off > 0; off >>= 1)
        acc += __shfl_down(acc, off, 64);
    __shared__ float smem[NTHR / 64];
    __shared__ int lastFlag;
    const int lane = threadIdx.x & 63;
    const int wid  = threadIdx.x >> 6;
    if (lane == 0) smem[wid] = acc;
    __syncthreads();
    if (threadIdx.x == 0) {
        float bsum = 0.0f;
        #pragma unroll
        for (int w = 0; w < NTHR / 64; ++w) bsum += smem[w];
        __hip_atomic_store(&partial[blockIdx.x], bsum,
                           __ATOMIC_RELEASE, __HIP_MEMORY_SCOPE_AGENT);
        int ticket = __hip_atomic_fetch_add(counter, 1,
                           __ATOMIC_ACQ_REL, __HIP_MEMORY_SCOPE_AGENT);
        lastFlag = (ticket == (int)gridDim.x - 1) ? 1 : 0;
    }
    __syncthreads();
    if (lastFlag) {
        // deterministic final reduction: fixed per-thread gather order
        float s = 0.0f;
        for (int j = threadIdx.x; j < (int)gridDim.x; j += NTHR)
            s += __hip_atomic_load(&partial[j],
                     __ATOMIC_RELAXED, __HIP_MEMORY_SCOPE_AGENT);
        #pragma unroll
        for (int off = 32; off > 0; off >>= 1)
            s += __shfl_down(s, off, 64);
        if (lane == 0) smem[wid] = s;
        __syncthreads();
        if (threadIdx.x == 0) {
            float tot = 0.0f;
            #pragma unroll
            for (int w = 0; w < NTHR / 64; ++w) tot += smem[w];
            out[0] = tot * invB;
        }
    }
}

extern "C" void kernel_launch(void* const* d_in, const int* in_sizes, int n_in,
                              void* d_out, int out_size, void* d_ws, size_t ws_size,
                              hipStream_t stream) {
    const float4* pred = (const float4*)d_in[0];
    const float4* targ = (const float4*)d_in[1];
    float* out = (float*)d_out;
    float* partial = (float*)d_ws;                       // NBLK floats
    int* counter   = (int*)((char*)d_ws + NBLK * sizeof(float));
    const int B = in_sizes[0] / 4;
    hipMemsetAsync(counter, 0, sizeof(int), stream);     // reset ticket each call
    drl_fused<<<NBLK, NTHR, 0, stream>>>(pred, targ, partial, counter, out,
                                         B, 1.0f / (float)B);
}

// Round 3
// 47.667 us; speedup vs baseline: 3.4800x; 3.4800x over previous
//
#include <hip/hip_runtime.h>
#include <math.h>

#define NBLK 2048
#define NTHR 256

// q fields: .x=w .y=x .z=y .w=z  (reference layout q[:,0..3] = w,x,y,z)
// Unnormalized rotation of REF=(0,0,1) by q:  u = |q|^2 * R(q_hat)*REF
//   u = ( 2(w*y + x*z), 2(y*z - w*x), |q|^2 - 2(x^2 + y^2) )
// The |q|^2 factor cancels under the final normalization, so the quat
// normalize (2 sqrt + 8 mul) is eliminated entirely.
__device__ __forceinline__ float row_angle2(float4 p, float4 t) {
    float n2p = p.x*p.x + p.y*p.y + p.z*p.z + p.w*p.w;
    float upx = 2.0f*(p.x*p.z + p.y*p.w);
    float upy = 2.0f*(p.z*p.w - p.x*p.y);
    float upz = n2p - 2.0f*(p.y*p.y + p.z*p.z);

    float n2t = t.x*t.x + t.y*t.y + t.z*t.z + t.w*t.w;
    float utx = 2.0f*(t.x*t.z + t.y*t.w);
    float uty = 2.0f*(t.z*t.w - t.x*t.y);
    float utz = n2t - 2.0f*(t.y*t.y + t.z*t.z);

    float d   = upx*utx + upy*uty + upz*utz;
    float mp  = upx*upx + upy*upy + upz*upz;
    float mt  = utx*utx + uty*uty + utz*utz;
    float m   = fmaxf(mp*mt, 1e-24f);
    float c   = d * rsqrtf(m);            // one hw v_rsq for both normalizes
    c = fminf(1.0f, fmaxf(-1.0f, c));

    // acos via Abramowitz-Stegun 4.4.45: |err| <= 6.7e-5 rad (thr 5.9e-2)
    float a = fabsf(c);
    float r = sqrtf(1.0f - a) *
              (1.5707288f + a*(-0.2121144f + a*(0.0742610f + a*(-0.0187293f))));
    float ang = (c >= 0.0f) ? r : 3.14159265358979f - r;
    return ang * ang;
}

__global__ __launch_bounds__(NTHR) void drl_main(
    const float4* __restrict__ pred,
    const float4* __restrict__ targ,
    float* __restrict__ partial,
    int B)
{
    const int tid = blockIdx.x * blockDim.x + threadIdx.x;
    const int stride = gridDim.x * blockDim.x;
    float acc = 0.0f;
    for (int i = tid; i < B; i += stride)
        acc += row_angle2(pred[i], targ[i]);

    #pragma unroll
    for (int off = 32; off > 0; off >>= 1)
        acc += __shfl_down(acc, off, 64);
    __shared__ float smem[NTHR / 64];
    const int lane = threadIdx.x & 63;
    const int wid  = threadIdx.x >> 6;
    if (lane == 0) smem[wid] = acc;
    __syncthreads();
    if (threadIdx.x == 0) {
        float s = 0.0f;
        #pragma unroll
        for (int w = 0; w < NTHR / 64; ++w) s += smem[w];
        partial[blockIdx.x] = s;
    }
}

__global__ __launch_bounds__(NTHR) void drl_finalize(
    const float* __restrict__ partial, float* __restrict__ out, int n, float invB)
{
    float acc = 0.0f;
    for (int i = threadIdx.x; i < n; i += blockDim.x) acc += partial[i];
    #pragma unroll
    for (int off = 32; off > 0; off >>= 1)
        acc += __shfl_down(acc, off, 64);
    __shared__ float smem[NTHR / 64];
    const int lane = threadIdx.x & 63;
    const int wid  = threadIdx.x >> 6;
    if (lane == 0) smem[wid] = acc;
    __syncthreads();
    if (threadIdx.x == 0) {
        float s = 0.0f;
        #pragma unroll
        for (int w = 0; w < NTHR / 64; ++w) s += smem[w];
        out[0] = s * invB;
    }
}

extern "C" void kernel_launch(void* const* d_in, const int* in_sizes, int n_in,
                              void* d_out, int out_size, void* d_ws, size_t ws_size,
                              hipStream_t stream) {
    const float4* pred = (const float4*)d_in[0];
    const float4* targ = (const float4*)d_in[1];
    float* out = (float*)d_out;
    float* partial = (float*)d_ws;   // NBLK floats of scratch
    const int B = in_sizes[0] / 4;
    drl_main<<<NBLK, NTHR, 0, stream>>>(pred, targ, partial, B);
    drl_finalize<<<1, NTHR, 0, stream>>>(partial, out, NBLK, 1.0f / (float)B);
}